// Round 2
// baseline (1395.490 us; speedup 1.0000x reference)
//
#include <hip/hip_runtime.h>
#include <stdint.h>

// All float tensors are float32 (per reference); batch is int32; output f32.
// d_ws layout: ws[0 .. G*6) = polar accumulator (f32), zeroed each call.
//
// Work decomposition: one block = 256 threads = 4 waves handles 64 nodes.
// Node index n = blockIdx.x*64 + lane (lane = tid&63).
// Wave s (tid>>6) owns j-columns [16s,16s+16) of the 64-wide GEMMs and
// k-rows [4s,4s+4) of the 16-wide einsum. All weight pointers depend only
// on s -> wave-uniform -> scalar loads. Per-wave partial sums are combined
// through a small padded LDS buffer (all outputs are linear reductions;
// biases are applied once, after the cross-wave sum).

__device__ __forceinline__ float fast_rcp(float x) {
    return __builtin_amdgcn_rcpf(x);
}

// 128 FMAs: acc[0..15] += 8-float input chunk (A0,A1) times 8x16 slab of W
// (row stride 64).
#define GEMM8x16(ACC, W, A0, A1)                                \
    _Pragma("unroll")                                           \
    for (int j = 0; j < 16; j++) {                              \
        float v = (ACC)[j];                                     \
        v = fmaf((A0).x, (W)[j],       v);                      \
        v = fmaf((A0).y, (W)[64 + j],  v);                      \
        v = fmaf((A0).z, (W)[128 + j], v);                      \
        v = fmaf((A0).w, (W)[192 + j], v);                      \
        v = fmaf((A1).x, (W)[256 + j], v);                      \
        v = fmaf((A1).y, (W)[320 + j], v);                      \
        v = fmaf((A1).z, (W)[384 + j], v);                      \
        v = fmaf((A1).w, (W)[448 + j], v);                      \
        (ACC)[j] = v;                                           \
    }

__global__ __launch_bounds__(256) void node_kernel(
    const float* __restrict__ node_scalar,  // (N,128)
    const float* __restrict__ node_equi,    // (N,480)
    const int*   __restrict__ batch,        // (N)
    const float* __restrict__ Weq0,         // (128,64) row-major
    const float* __restrict__ beq0,         // (64)
    const float* __restrict__ Weq2,         // (32,16) row-major
    const float* __restrict__ Wout0,        // (64)
    const float* __restrict__ bout0,        // (1)
    const float* __restrict__ Wout2,        // (16)
    const float* __restrict__ Ws1,          // (128,64) row-major
    const float* __restrict__ bs1,          // (64)
    const float* __restrict__ Ws2,          // (64,2) row-major
    const float* __restrict__ bs2,          // (2)
    float* __restrict__ polar,              // (G,6) f32 accumulator
    int N)
{
    const int lane = threadIdx.x & 63;
    const int s    = threadIdx.x >> 6;          // wave id 0..3 (wave-uniform)
    const int n    = blockIdx.x * 64 + lane;
    const bool valid = (n < N);
    const int n_ld = valid ? n : (N - 1);       // clamp loads; no early return
                                                // (everyone must hit barrier)

    // ---------- phase 1: partial of s = silu(ns@Ws1+bs1)@Ws2 ---------------
    float acc[16];
#pragma unroll
    for (int j = 0; j < 16; j++) acc[j] = 0.f;
    const float4* nsr = (const float4*)(node_scalar + (size_t)n_ld * 128);
    {
        float4 a0 = nsr[0], a1 = nsr[1];        // chunk 0
#pragma unroll 1
        for (int c = 0; c < 15; c++) {
            float4 b0 = nsr[2 * c + 2], b1 = nsr[2 * c + 3];  // prefetch c+1
            const float* w = Ws1 + c * 512 + s * 16;          // wave-uniform
            GEMM8x16(acc, w, a0, a1);
            a0 = b0; a1 = b1;
        }
        GEMM8x16(acc, Ws1 + 15 * 512 + s * 16, a0, a1);       // peeled tail
    }
    float sAp = 0.f, sBp = 0.f;                 // raw partials (bias later)
#pragma unroll
    for (int j = 0; j < 16; j++) {
        int jg = s * 16 + j;
        float h = acc[j] + bs1[jg];
        float t = h * fast_rcp(1.f + __expf(-h));      // silu(h)
        sAp = fmaf(t, Ws2[2 * jg],     sAp);
        sBp = fmaf(t, Ws2[2 * jg + 1], sBp);
    }

    // ---------- phase 2: partial of o0 = g0 @ Wout0 -------------------------
#pragma unroll
    for (int j = 0; j < 16; j++) acc[j] = 0.f;
    const float4* x0r = (const float4*)(node_equi + (size_t)n_ld * 480);
    {
        float4 a0 = x0r[0], a1 = x0r[1];
#pragma unroll 1
        for (int c = 0; c < 15; c++) {
            float4 b0 = x0r[2 * c + 2], b1 = x0r[2 * c + 3];
            const float* w = Weq0 + c * 512 + s * 16;
            GEMM8x16(acc, w, a0, a1);
            a0 = b0; a1 = b1;
        }
        GEMM8x16(acc, Weq0 + 15 * 512 + s * 16, a0, a1);
    }
    float o0p = 0.f;
#pragma unroll
    for (int j = 0; j < 16; j++) {
        int jg = s * 16 + j;
        float h = fmaf(acc[j], 0.08838834764831845f, beq0[jg]); // *128^-0.5+b
        float r = sqrtf(fmaf(h, h, 1e-12f));            // sqrt(h^2 + EPS)
        float g = h * (r * fast_rcp(1.f + __expf(-r))); // h * silu(r)
        o0p = fmaf(g, Wout0[jg], o0p);
    }

    // ---------- phase 3: partial of o2 (this wave's 4 k's) ------------------
    float acc2[20];                             // [kk*5 + i], k = s*4 + kk
#pragma unroll
    for (int t = 0; t < 20; t++) acc2[t] = 0.f;
    const float4* x2r = (const float4*)(node_equi + (size_t)n_ld * 480 + 320);
#pragma unroll 1
    for (int mc = 0; mc < 8; mc++) {            // 4 m's (20 floats) per iter
        float4 c0 = x2r[mc * 5 + 0], c1 = x2r[mc * 5 + 1],
               c2 = x2r[mc * 5 + 2], c3 = x2r[mc * 5 + 3],
               c4 = x2r[mc * 5 + 4];
        float f[20] = { c0.x, c0.y, c0.z, c0.w, c1.x,
                        c1.y, c1.z, c1.w, c2.x, c2.y,
                        c2.z, c2.w, c3.x, c3.y, c3.z,
                        c3.w, c4.x, c4.y, c4.z, c4.w };
#pragma unroll
        for (int mm = 0; mm < 4; mm++) {
            float v0 = f[mm * 5 + 0], v1 = f[mm * 5 + 1],
                  v2 = f[mm * 5 + 2], v3 = f[mm * 5 + 3],
                  v4 = f[mm * 5 + 4];
            const float* wq = Weq2 + (mc * 4 + mm) * 16 + s * 4; // uniform
#pragma unroll
            for (int kk = 0; kk < 4; kk++) {
                float wk = wq[kk];
                acc2[kk * 5 + 0] = fmaf(v0, wk, acc2[kk * 5 + 0]);
                acc2[kk * 5 + 1] = fmaf(v1, wk, acc2[kk * 5 + 1]);
                acc2[kk * 5 + 2] = fmaf(v2, wk, acc2[kk * 5 + 2]);
                acc2[kk * 5 + 3] = fmaf(v3, wk, acc2[kk * 5 + 3]);
                acc2[kk * 5 + 4] = fmaf(v4, wk, acc2[kk * 5 + 4]);
            }
        }
    }
    float o2p[5] = { 0.f, 0.f, 0.f, 0.f, 0.f };
    const float S32 = 0.17677669529663687f;     // 32^-0.5
#pragma unroll
    for (int kk = 0; kk < 4; kk++) {
        float h0 = acc2[kk * 5 + 0] * S32, h1 = acc2[kk * 5 + 1] * S32,
              h2 = acc2[kk * 5 + 2] * S32, h3 = acc2[kk * 5 + 3] * S32,
              h4 = acc2[kk * 5 + 4] * S32;
        float nn = sqrtf(h0 * h0 + h1 * h1 + h2 * h2 + h3 * h3 +
                         h4 * h4 + 1e-12f);
        float sil = nn * fast_rcp(1.f + __expf(-nn));  // silu(n2)
        float fct = sil * Wout2[s * 4 + kk];
        o2p[0] = fmaf(h0, fct, o2p[0]); o2p[1] = fmaf(h1, fct, o2p[1]);
        o2p[2] = fmaf(h2, fct, o2p[2]); o2p[3] = fmaf(h3, fct, o2p[3]);
        o2p[4] = fmaf(h4, fct, o2p[4]);
    }

    // ---------- cross-wave reduction + segment-sum --------------------------
    __shared__ float red[4][64][9];             // 9-padded: conflict-free
    {
        float* r = &red[s][lane][0];
        r[0] = sAp; r[1] = sBp; r[2] = o0p;
        r[3] = o2p[0]; r[4] = o2p[1]; r[5] = o2p[2];
        r[6] = o2p[3]; r[7] = o2p[4];
    }
    __syncthreads();
    if (s == 0 && valid) {
        float vA = 0.f, vB = 0.f, v0 = 0.f,
              w0 = 0.f, w1 = 0.f, w2 = 0.f, w3 = 0.f, w4 = 0.f;
#pragma unroll
        for (int w = 0; w < 4; w++) {
            const float* q = &red[w][lane][0];
            vA += q[0]; vB += q[1]; v0 += q[2];
            w0 += q[3]; w1 += q[4]; w2 += q[5]; w3 += q[6]; w4 += q[7];
        }
        float sA = vA + bs2[0];
        float sB = vB + bs2[1];
        float o0 = fmaf(v0, 0.125f, bout0[0]);  // *64^-0.5 + b (bias once)
        int b = batch[n];
        float* p = polar + (size_t)b * 6;
        atomicAdd(p + 0, o0 * sA);
        float q2 = 0.25f * sB;                  // 16^-0.5 * s[:,1]
        atomicAdd(p + 1, w0 * q2);
        atomicAdd(p + 2, w1 * q2);
        atomicAdd(p + 3, w2 * q2);
        atomicAdd(p + 4, w3 * q2);
        atomicAdd(p + 5, w4 * q2);
    }
}

__global__ __launch_bounds__(256) void finalize_kernel(
    const float* __restrict__ polar, float* __restrict__ out, int G)
{
    int g = blockIdx.x * 256 + threadIdx.x;
    if (g >= G) return;
    const float* p = polar + (size_t)g * 6;
    float z = p[0], dxy = p[1], dyz = p[2], dz2 = p[3], dzx = p[4], dx2 = p[5];
    float dn = sqrtf(dxy * dxy + dyz * dyz + dz2 * dz2 + dzx * dzx + dx2 * dx2);
    const float c = 0.57735026918962576f;       // 3^-0.5
    float xx = c * (dn - dz2) + dx2 + z;
    float yy = c * (dn - dz2) - dx2 + z;
    float zz = c * (dn + 2.f * dz2) + z;
    float* o = out + (size_t)g * 9;
    o[0] = xx;  o[1] = dxy; o[2] = dzx;
    o[3] = dxy; o[4] = yy;  o[5] = dyz;
    o[6] = dzx; o[7] = dyz; o[8] = zz;
}

extern "C" void kernel_launch(void* const* d_in, const int* in_sizes, int n_in,
                              void* d_out, int out_size, void* d_ws, size_t ws_size,
                              hipStream_t stream) {
    const float* node_scalar = (const float*)d_in[0];
    const float* node_equi   = (const float*)d_in[1];
    const int*   batch       = (const int*)d_in[2];
    const float* Weq0  = (const float*)d_in[3];
    const float* beq0  = (const float*)d_in[4];
    const float* Weq2  = (const float*)d_in[5];
    const float* Wout0 = (const float*)d_in[6];
    const float* bout0 = (const float*)d_in[7];
    const float* Wout2 = (const float*)d_in[8];
    const float* Ws1   = (const float*)d_in[9];
    const float* bs1   = (const float*)d_in[10];
    const float* Ws2   = (const float*)d_in[11];
    const float* bs2   = (const float*)d_in[12];

    int N = in_sizes[0] / 128;
    int G = out_size / 9;
    float* polar = (float*)d_ws;

    hipMemsetAsync(polar, 0, (size_t)G * 6 * sizeof(float), stream);

    node_kernel<<<(N + 63) / 64, 256, 0, stream>>>(
        node_scalar, node_equi, batch,
        Weq0, beq0, Weq2, Wout0, bout0, Wout2, Ws1, bs1, Ws2, bs2,
        polar, N);

    finalize_kernel<<<(G + 255) / 256, 256, 0, stream>>>(
        polar, (float*)d_out, G);
}

// Round 3
// 945.273 us; speedup vs baseline: 1.4763x; 1.4763x over previous
//
#include <hip/hip_runtime.h>
#include <stdint.h>

// All float tensors are float32 (per reference); batch is int32; output f32.
// d_ws layout: ws[0 .. G*6) = polar accumulator (f32), zeroed each call.
//
// One thread = one node. To keep natural VGPR pressure < 128 (so the grid's
// 4 waves/SIMD all fit with ZERO spills), the 64-wide GEMMs are computed in
// two sequential 32-column halves (acc[32]) and the 32x16x5 einsum in four
// sequential 4-k quarters (acc2q[20]). Inputs are re-read per pass; the
// repeats hit L1/L2. Weight pointers depend only on loop constants ->
// wave-uniform -> s_load scalar streams (the R2 regression was losing this).

__device__ __forceinline__ float fast_rcp(float x) {
    return __builtin_amdgcn_rcpf(x);
}

// 256 FMAs: acc[0..31] += 8-float input chunk (A0,A1) times 8x32 slab of W
// (row stride 64 floats).
#define GEMM8x32(ACC, W, A0, A1)                                \
    _Pragma("unroll")                                           \
    for (int j = 0; j < 32; j++) {                              \
        float v = (ACC)[j];                                     \
        v = fmaf((A0).x, (W)[j],       v);                      \
        v = fmaf((A0).y, (W)[64 + j],  v);                      \
        v = fmaf((A0).z, (W)[128 + j], v);                      \
        v = fmaf((A0).w, (W)[192 + j], v);                      \
        v = fmaf((A1).x, (W)[256 + j], v);                      \
        v = fmaf((A1).y, (W)[320 + j], v);                      \
        v = fmaf((A1).z, (W)[384 + j], v);                      \
        v = fmaf((A1).w, (W)[448 + j], v);                      \
        (ACC)[j] = v;                                           \
    }

__global__ __launch_bounds__(256) void node_kernel(
    const float* __restrict__ node_scalar,  // (N,128)
    const float* __restrict__ node_equi,    // (N,480)
    const int*   __restrict__ batch,        // (N)
    const float* __restrict__ Weq0,         // (128,64) row-major
    const float* __restrict__ beq0,         // (64)
    const float* __restrict__ Weq2,         // (32,16) row-major
    const float* __restrict__ Wout0,        // (64)
    const float* __restrict__ bout0,        // (1)
    const float* __restrict__ Wout2,        // (16)
    const float* __restrict__ Ws1,          // (128,64) row-major
    const float* __restrict__ bs1,          // (64)
    const float* __restrict__ Ws2,          // (64,2) row-major
    const float* __restrict__ bs2,          // (2)
    float* __restrict__ polar,              // (G,6) f32 accumulator
    int N)
{
    int n = blockIdx.x * 256 + threadIdx.x;
    if (n >= N) return;
    int b = batch[n];

    // ---------- phase 1: s = silu(ns@Ws1 + bs1) @ Ws2 + bs2 ----------------
    float sA = bs2[0], sB = bs2[1];
    const float4* nsr = (const float4*)(node_scalar + (size_t)n * 128);
#pragma unroll 1
    for (int half = 0; half < 2; half++) {
        float acc[32];
#pragma unroll
        for (int j = 0; j < 32; j++) acc[j] = 0.f;
        {
            float4 a0 = nsr[0], a1 = nsr[1];        // chunk 0
#pragma unroll 1
            for (int c = 0; c < 15; c++) {
                float4 b0 = nsr[2 * c + 2], b1 = nsr[2 * c + 3]; // prefetch
                const float* w = Ws1 + c * 512 + half * 32;      // uniform
                GEMM8x32(acc, w, a0, a1);
                a0 = b0; a1 = b1;
            }
            GEMM8x32(acc, Ws1 + 15 * 512 + half * 32, a0, a1);   // tail
        }
#pragma unroll
        for (int j = 0; j < 32; j++) {
            int jg = half * 32 + j;
            float h = acc[j] + bs1[jg];
            float t = h * fast_rcp(1.f + __expf(-h));    // silu(h)
            sA = fmaf(t, Ws2[2 * jg],     sA);
            sB = fmaf(t, Ws2[2 * jg + 1], sB);
        }
    }

    // ---------- phase 2: o0 = (g0 @ Wout0) * 64^-0.5 + b --------------------
    float o0 = 0.f;
    const float4* x0r = (const float4*)(node_equi + (size_t)n * 480);
#pragma unroll 1
    for (int half = 0; half < 2; half++) {
        float acc[32];
#pragma unroll
        for (int j = 0; j < 32; j++) acc[j] = 0.f;
        {
            float4 a0 = x0r[0], a1 = x0r[1];
#pragma unroll 1
            for (int c = 0; c < 15; c++) {
                float4 b0 = x0r[2 * c + 2], b1 = x0r[2 * c + 3];
                const float* w = Weq0 + c * 512 + half * 32;
                GEMM8x32(acc, w, a0, a1);
                a0 = b0; a1 = b1;
            }
            GEMM8x32(acc, Weq0 + 15 * 512 + half * 32, a0, a1);
        }
#pragma unroll
        for (int j = 0; j < 32; j++) {
            int jg = half * 32 + j;
            float h = fmaf(acc[j], 0.08838834764831845f, beq0[jg]); // scale+b
            float r = sqrtf(fmaf(h, h, 1e-12f));            // sqrt(h^2+EPS)
            float g = h * (r * fast_rcp(1.f + __expf(-r))); // h*silu(r)
            o0 = fmaf(g, Wout0[jg], o0);
        }
    }
    o0 = fmaf(o0, 0.125f, bout0[0]);               // *64^-0.5 + b

    // ---------- phase 3: o2 path, four 4-k quarters -------------------------
    // k ascending across quarters, m ascending within -> same accumulation
    // order as the monolithic version.
    const float4* x2r = (const float4*)(node_equi + (size_t)n * 480 + 320);
    float o2[5] = { 0.f, 0.f, 0.f, 0.f, 0.f };
    const float S32 = 0.17677669529663687f;        // 32^-0.5
#pragma unroll 1
    for (int kq = 0; kq < 4; kq++) {
        float acc2q[20];                           // [kk*5 + i], k = kq*4+kk
#pragma unroll
        for (int t = 0; t < 20; t++) acc2q[t] = 0.f;
        float4 c0 = x2r[0], c1 = x2r[1], c2 = x2r[2], c3 = x2r[3], c4 = x2r[4];
#pragma unroll 1
        for (int mc = 0; mc < 8; mc++) {           // 4 m's (20 floats) / iter
            float4 n0, n1, n2, n3, n4;
            if (mc < 7) {
                n0 = x2r[mc * 5 + 5]; n1 = x2r[mc * 5 + 6];
                n2 = x2r[mc * 5 + 7]; n3 = x2r[mc * 5 + 8];
                n4 = x2r[mc * 5 + 9];
            }
            const float* wq = Weq2 + (mc * 4) * 16 + kq * 4;  // uniform
#define EINS_M(V0, V1, V2, V3, V4, MM)                                  \
            {                                                           \
                const float* wr = wq + (MM) * 16;                       \
                _Pragma("unroll")                                       \
                for (int kk = 0; kk < 4; kk++) {                        \
                    float wk = wr[kk];                                  \
                    acc2q[kk * 5 + 0] = fmaf((V0), wk, acc2q[kk * 5 + 0]); \
                    acc2q[kk * 5 + 1] = fmaf((V1), wk, acc2q[kk * 5 + 1]); \
                    acc2q[kk * 5 + 2] = fmaf((V2), wk, acc2q[kk * 5 + 2]); \
                    acc2q[kk * 5 + 3] = fmaf((V3), wk, acc2q[kk * 5 + 3]); \
                    acc2q[kk * 5 + 4] = fmaf((V4), wk, acc2q[kk * 5 + 4]); \
                }                                                       \
            }
            EINS_M(c0.x, c0.y, c0.z, c0.w, c1.x, 0)
            EINS_M(c1.y, c1.z, c1.w, c2.x, c2.y, 1)
            EINS_M(c2.z, c2.w, c3.x, c3.y, c3.z, 2)
            EINS_M(c3.w, c4.x, c4.y, c4.z, c4.w, 3)
#undef EINS_M
            c0 = n0; c1 = n1; c2 = n2; c3 = n3; c4 = n4;
        }
#pragma unroll
        for (int kk = 0; kk < 4; kk++) {
            float h0 = acc2q[kk * 5 + 0] * S32, h1 = acc2q[kk * 5 + 1] * S32,
                  h2 = acc2q[kk * 5 + 2] * S32, h3 = acc2q[kk * 5 + 3] * S32,
                  h4 = acc2q[kk * 5 + 4] * S32;
            float nn = sqrtf(h0 * h0 + h1 * h1 + h2 * h2 + h3 * h3 +
                             h4 * h4 + 1e-12f);
            float sil = nn * fast_rcp(1.f + __expf(-nn));  // silu(n2)
            float fct = sil * Wout2[kq * 4 + kk];
            o2[0] = fmaf(h0, fct, o2[0]); o2[1] = fmaf(h1, fct, o2[1]);
            o2[2] = fmaf(h2, fct, o2[2]); o2[3] = fmaf(h3, fct, o2[3]);
            o2[4] = fmaf(h4, fct, o2[4]);
        }
    }

    // ---------- segment-sum -------------------------------------------------
    float* p = polar + (size_t)b * 6;
    atomicAdd(p + 0, o0 * sA);
    float q = 0.25f * sB;                          // 16^-0.5 * s[:,1]
    atomicAdd(p + 1, o2[0] * q);
    atomicAdd(p + 2, o2[1] * q);
    atomicAdd(p + 3, o2[2] * q);
    atomicAdd(p + 4, o2[3] * q);
    atomicAdd(p + 5, o2[4] * q);
}

__global__ __launch_bounds__(256) void finalize_kernel(
    const float* __restrict__ polar, float* __restrict__ out, int G)
{
    int g = blockIdx.x * 256 + threadIdx.x;
    if (g >= G) return;
    const float* p = polar + (size_t)g * 6;
    float z = p[0], dxy = p[1], dyz = p[2], dz2 = p[3], dzx = p[4], dx2 = p[5];
    float dn = sqrtf(dxy * dxy + dyz * dyz + dz2 * dz2 + dzx * dzx + dx2 * dx2);
    const float c = 0.57735026918962576f;          // 3^-0.5
    float xx = c * (dn - dz2) + dx2 + z;
    float yy = c * (dn - dz2) - dx2 + z;
    float zz = c * (dn + 2.f * dz2) + z;
    float* o = out + (size_t)g * 9;
    o[0] = xx;  o[1] = dxy; o[2] = dzx;
    o[3] = dxy; o[4] = yy;  o[5] = dyz;
    o[6] = dzx; o[7] = dyz; o[8] = zz;
}

extern "C" void kernel_launch(void* const* d_in, const int* in_sizes, int n_in,
                              void* d_out, int out_size, void* d_ws, size_t ws_size,
                              hipStream_t stream) {
    const float* node_scalar = (const float*)d_in[0];
    const float* node_equi   = (const float*)d_in[1];
    const int*   batch       = (const int*)d_in[2];
    const float* Weq0  = (const float*)d_in[3];
    const float* beq0  = (const float*)d_in[4];
    const float* Weq2  = (const float*)d_in[5];
    const float* Wout0 = (const float*)d_in[6];
    const float* bout0 = (const float*)d_in[7];
    const float* Wout2 = (const float*)d_in[8];
    const float* Ws1   = (const float*)d_in[9];
    const float* bs1   = (const float*)d_in[10];
    const float* Ws2   = (const float*)d_in[11];
    const float* bs2   = (const float*)d_in[12];

    int N = in_sizes[0] / 128;
    int G = out_size / 9;
    float* polar = (float*)d_ws;

    hipMemsetAsync(polar, 0, (size_t)G * 6 * sizeof(float), stream);

    node_kernel<<<(N + 255) / 256, 256, 0, stream>>>(
        node_scalar, node_equi, batch,
        Weq0, beq0, Weq2, Wout0, bout0, Wout2, Ws1, bs1, Ws2, bs2,
        polar, N);

    finalize_kernel<<<(G + 255) / 256, 256, 0, stream>>>(
        polar, (float*)d_out, G);
}

// Round 4
// 873.770 us; speedup vs baseline: 1.5971x; 1.0818x over previous
//
#include <hip/hip_runtime.h>
#include <stdint.h>

// All float tensors are float32 (per reference); batch is int32; output f32.
// d_ws layout: ws[0 .. G*6) = polar accumulator (f32), zeroed each call.
//
// Decomposition (R2 structure, fixed): one block = 256 threads = 4 waves
// handles 64 nodes; n = blockIdx.x*64 + lane. Wave s owns j-columns
// [16s,16s+16) of the 64-wide GEMMs and k-rows [4s,4s+4) of the einsum.
// CRITICAL: s is forced into an SGPR via readfirstlane so every weight
// address is wave-uniform -> s_load scalar streams. (R2 regressed because
// the compiler kept s per-lane -> vector weight loads -> VGPR 228.)
// The 4 waves read the same 64 input rows (32KB) -> L1 absorbs the reuse;
// HBM traffic stays at one pass over the inputs (R3's re-read penalty gone).
// Partials are combined through a 9-padded LDS buffer; biases applied once.

__device__ __forceinline__ float fast_rcp(float x) {
    return __builtin_amdgcn_rcpf(x);
}

// 128 FMAs: acc[0..15] += 8-float input chunk (A0,A1) times 8x16 slab of W
// (row stride 64 floats).
#define GEMM8x16(ACC, W, A0, A1)                                \
    _Pragma("unroll")                                           \
    for (int j = 0; j < 16; j++) {                              \
        float v = (ACC)[j];                                     \
        v = fmaf((A0).x, (W)[j],       v);                      \
        v = fmaf((A0).y, (W)[64 + j],  v);                      \
        v = fmaf((A0).z, (W)[128 + j], v);                      \
        v = fmaf((A0).w, (W)[192 + j], v);                      \
        v = fmaf((A1).x, (W)[256 + j], v);                      \
        v = fmaf((A1).y, (W)[320 + j], v);                      \
        v = fmaf((A1).z, (W)[384 + j], v);                      \
        v = fmaf((A1).w, (W)[448 + j], v);                      \
        (ACC)[j] = v;                                           \
    }

__global__ __launch_bounds__(256) void node_kernel(
    const float* __restrict__ node_scalar,  // (N,128)
    const float* __restrict__ node_equi,    // (N,480)
    const int*   __restrict__ batch,        // (N)
    const float* __restrict__ Weq0,         // (128,64) row-major
    const float* __restrict__ beq0,         // (64)
    const float* __restrict__ Weq2,         // (32,16) row-major
    const float* __restrict__ Wout0,        // (64)
    const float* __restrict__ bout0,        // (1)
    const float* __restrict__ Wout2,        // (16)
    const float* __restrict__ Ws1,          // (128,64) row-major
    const float* __restrict__ bs1,          // (64)
    const float* __restrict__ Ws2,          // (64,2) row-major
    const float* __restrict__ bs2,          // (2)
    float* __restrict__ polar,              // (G,6) f32 accumulator
    int N)
{
    const int lane = threadIdx.x & 63;
    // Force wave id into an SGPR: weight addresses must be wave-uniform.
    const int s = __builtin_amdgcn_readfirstlane(threadIdx.x >> 6);
    const int n = blockIdx.x * 64 + lane;
    const bool valid = (n < N);
    const int n_ld = valid ? n : (N - 1);   // clamp loads; all threads must
                                            // reach the barrier below

    // ---------- phase 1: partial of s = silu(ns@Ws1+bs1)@Ws2 ---------------
    float acc[16];
#pragma unroll
    for (int j = 0; j < 16; j++) acc[j] = 0.f;
    const float4* nsr = (const float4*)(node_scalar + (size_t)n_ld * 128);
    const float* wS1 = Ws1 + s * 16;        // SGPR base
    {
        float4 a0 = nsr[0], a1 = nsr[1];    // chunk 0
#pragma unroll 1
        for (int c = 0; c < 15; c++) {
            float4 b0 = nsr[2 * c + 2], b1 = nsr[2 * c + 3];  // prefetch c+1
            const float* w = wS1 + c * 512;                   // scalar stream
            GEMM8x16(acc, w, a0, a1);
            a0 = b0; a1 = b1;
        }
        GEMM8x16(acc, wS1 + 15 * 512, a0, a1);                // peeled tail
    }
    float sAp = 0.f, sBp = 0.f;             // raw partials (bias later)
#pragma unroll
    for (int j = 0; j < 16; j++) {
        int jg = s * 16 + j;                // SGPR index
        float h = acc[j] + bs1[jg];
        float t = h * fast_rcp(1.f + __expf(-h));      // silu(h)
        sAp = fmaf(t, Ws2[2 * jg],     sAp);
        sBp = fmaf(t, Ws2[2 * jg + 1], sBp);
    }

    // ---------- phase 2: partial of o0 = g0 @ Wout0 -------------------------
#pragma unroll
    for (int j = 0; j < 16; j++) acc[j] = 0.f;
    const float4* x0r = (const float4*)(node_equi + (size_t)n_ld * 480);
    const float* wE0 = Weq0 + s * 16;       // SGPR base
    {
        float4 a0 = x0r[0], a1 = x0r[1];
#pragma unroll 1
        for (int c = 0; c < 15; c++) {
            float4 b0 = x0r[2 * c + 2], b1 = x0r[2 * c + 3];
            const float* w = wE0 + c * 512;
            GEMM8x16(acc, w, a0, a1);
            a0 = b0; a1 = b1;
        }
        GEMM8x16(acc, wE0 + 15 * 512, a0, a1);
    }
    float o0p = 0.f;
#pragma unroll
    for (int j = 0; j < 16; j++) {
        int jg = s * 16 + j;
        float h = fmaf(acc[j], 0.08838834764831845f, beq0[jg]); // *128^-0.5+b
        float r = sqrtf(fmaf(h, h, 1e-12f));            // sqrt(h^2 + EPS)
        float g = h * (r * fast_rcp(1.f + __expf(-r))); // h * silu(r)
        o0p = fmaf(g, Wout0[jg], o0p);
    }

    // ---------- phase 3: partial of o2 (this wave's 4 k's) ------------------
    float acc2[20];                         // [kk*5 + i], k = s*4 + kk
#pragma unroll
    for (int t = 0; t < 20; t++) acc2[t] = 0.f;
    const float4* x2r = (const float4*)(node_equi + (size_t)n_ld * 480 + 320);
    const float* wE2 = Weq2 + s * 4;        // SGPR base
    {
        float4 c0 = x2r[0], c1 = x2r[1], c2 = x2r[2], c3 = x2r[3], c4 = x2r[4];
#pragma unroll 1
        for (int mc = 0; mc < 8; mc++) {    // 4 m's (20 floats) per iter
            float4 n0, n1, n2, n3, n4;
            if (mc < 7) {
                n0 = x2r[mc * 5 + 5]; n1 = x2r[mc * 5 + 6];
                n2 = x2r[mc * 5 + 7]; n3 = x2r[mc * 5 + 8];
                n4 = x2r[mc * 5 + 9];
            }
            const float* wq = wE2 + mc * 64;                  // scalar stream
#define EINS_M(V0, V1, V2, V3, V4, MM)                                  \
            {                                                           \
                const float* wr = wq + (MM) * 16;                       \
                _Pragma("unroll")                                       \
                for (int kk = 0; kk < 4; kk++) {                        \
                    float wk = wr[kk];                                  \
                    acc2[kk * 5 + 0] = fmaf((V0), wk, acc2[kk * 5 + 0]); \
                    acc2[kk * 5 + 1] = fmaf((V1), wk, acc2[kk * 5 + 1]); \
                    acc2[kk * 5 + 2] = fmaf((V2), wk, acc2[kk * 5 + 2]); \
                    acc2[kk * 5 + 3] = fmaf((V3), wk, acc2[kk * 5 + 3]); \
                    acc2[kk * 5 + 4] = fmaf((V4), wk, acc2[kk * 5 + 4]); \
                }                                                       \
            }
            EINS_M(c0.x, c0.y, c0.z, c0.w, c1.x, 0)
            EINS_M(c1.y, c1.z, c1.w, c2.x, c2.y, 1)
            EINS_M(c2.z, c2.w, c3.x, c3.y, c3.z, 2)
            EINS_M(c3.w, c4.x, c4.y, c4.z, c4.w, 3)
#undef EINS_M
            c0 = n0; c1 = n1; c2 = n2; c3 = n3; c4 = n4;
        }
    }
    float o2p[5] = { 0.f, 0.f, 0.f, 0.f, 0.f };
    const float S32 = 0.17677669529663687f; // 32^-0.5
#pragma unroll
    for (int kk = 0; kk < 4; kk++) {
        float h0 = acc2[kk * 5 + 0] * S32, h1 = acc2[kk * 5 + 1] * S32,
              h2 = acc2[kk * 5 + 2] * S32, h3 = acc2[kk * 5 + 3] * S32,
              h4 = acc2[kk * 5 + 4] * S32;
        float nn = sqrtf(h0 * h0 + h1 * h1 + h2 * h2 + h3 * h3 +
                         h4 * h4 + 1e-12f);
        float sil = nn * fast_rcp(1.f + __expf(-nn));  // silu(n2)
        float fct = sil * Wout2[s * 4 + kk];
        o2p[0] = fmaf(h0, fct, o2p[0]); o2p[1] = fmaf(h1, fct, o2p[1]);
        o2p[2] = fmaf(h2, fct, o2p[2]); o2p[3] = fmaf(h3, fct, o2p[3]);
        o2p[4] = fmaf(h4, fct, o2p[4]);
    }

    // ---------- cross-wave reduction + segment-sum --------------------------
    __shared__ float red[4][64][9];         // 9-padded: conflict-free
    {
        float* r = &red[s][lane][0];
        r[0] = sAp; r[1] = sBp; r[2] = o0p;
        r[3] = o2p[0]; r[4] = o2p[1]; r[5] = o2p[2];
        r[6] = o2p[3]; r[7] = o2p[4];
    }
    __syncthreads();
    if (s == 0 && valid) {
        float vA = 0.f, vB = 0.f, v0 = 0.f,
              w0 = 0.f, w1 = 0.f, w2 = 0.f, w3 = 0.f, w4 = 0.f;
#pragma unroll
        for (int w = 0; w < 4; w++) {
            const float* q = &red[w][lane][0];
            vA += q[0]; vB += q[1]; v0 += q[2];
            w0 += q[3]; w1 += q[4]; w2 += q[5]; w3 += q[6]; w4 += q[7];
        }
        float sA = vA + bs2[0];
        float sB = vB + bs2[1];
        float o0 = fmaf(v0, 0.125f, bout0[0]);   // *64^-0.5 + b (bias once)
        int b = batch[n];
        float* p = polar + (size_t)b * 6;
        atomicAdd(p + 0, o0 * sA);
        float q2 = 0.25f * sB;                   // 16^-0.5 * s[:,1]
        atomicAdd(p + 1, w0 * q2);
        atomicAdd(p + 2, w1 * q2);
        atomicAdd(p + 3, w2 * q2);
        atomicAdd(p + 4, w3 * q2);
        atomicAdd(p + 5, w4 * q2);
    }
}

__global__ __launch_bounds__(256) void finalize_kernel(
    const float* __restrict__ polar, float* __restrict__ out, int G)
{
    int g = blockIdx.x * 256 + threadIdx.x;
    if (g >= G) return;
    const float* p = polar + (size_t)g * 6;
    float z = p[0], dxy = p[1], dyz = p[2], dz2 = p[3], dzx = p[4], dx2 = p[5];
    float dn = sqrtf(dxy * dxy + dyz * dyz + dz2 * dz2 + dzx * dzx + dx2 * dx2);
    const float c = 0.57735026918962576f;        // 3^-0.5
    float xx = c * (dn - dz2) + dx2 + z;
    float yy = c * (dn - dz2) - dx2 + z;
    float zz = c * (dn + 2.f * dz2) + z;
    float* o = out + (size_t)g * 9;
    o[0] = xx;  o[1] = dxy; o[2] = dzx;
    o[3] = dxy; o[4] = yy;  o[5] = dyz;
    o[6] = dzx; o[7] = dyz; o[8] = zz;
}

extern "C" void kernel_launch(void* const* d_in, const int* in_sizes, int n_in,
                              void* d_out, int out_size, void* d_ws, size_t ws_size,
                              hipStream_t stream) {
    const float* node_scalar = (const float*)d_in[0];
    const float* node_equi   = (const float*)d_in[1];
    const int*   batch       = (const int*)d_in[2];
    const float* Weq0  = (const float*)d_in[3];
    const float* beq0  = (const float*)d_in[4];
    const float* Weq2  = (const float*)d_in[5];
    const float* Wout0 = (const float*)d_in[6];
    const float* bout0 = (const float*)d_in[7];
    const float* Wout2 = (const float*)d_in[8];
    const float* Ws1   = (const float*)d_in[9];
    const float* bs1   = (const float*)d_in[10];
    const float* Ws2   = (const float*)d_in[11];
    const float* bs2   = (const float*)d_in[12];

    int N = in_sizes[0] / 128;
    int G = out_size / 9;
    float* polar = (float*)d_ws;

    hipMemsetAsync(polar, 0, (size_t)G * 6 * sizeof(float), stream);

    node_kernel<<<(N + 63) / 64, 256, 0, stream>>>(
        node_scalar, node_equi, batch,
        Weq0, beq0, Weq2, Wout0, bout0, Wout2, Ws1, bs1, Ws2, bs2,
        polar, N);

    finalize_kernel<<<(G + 255) / 256, 256, 0, stream>>>(
        polar, (float*)d_out, G);
}